// Round 5
// baseline (285.205 us; speedup 1.0000x reference)
//
#include <hip/hip_runtime.h>
#include <hip/hip_bf16.h>
#include <math.h>

#define NNODES 4096
#define NHEADS 4
#define MAXDEG 128

typedef __attribute__((ext_vector_type(8))) short  bf16x8;
typedef __attribute__((ext_vector_type(4))) float  f32x4;
typedef __attribute__((ext_vector_type(4))) unsigned short us4;

__device__ __forceinline__ unsigned short f2bf(float v) {
    unsigned int x = __float_as_uint(v);
    unsigned int r = (x + 0x7fffu + ((x >> 16) & 1u)) >> 16;   // RNE
    return (unsigned short)r;
}

__device__ __forceinline__ void gload_lds16(const unsigned short* g, unsigned short* l) {
    __builtin_amdgcn_global_load_lds(
        (const __attribute__((address_space(1))) unsigned int*)(g),
        (__attribute__((address_space(3))) unsigned int*)(l), 16, 0, 0);
}

// ---------------- CSR build with bitmap dedupe ----------------
__global__ __launch_bounds__(256) void build_csr(
    const int* __restrict__ er, const int* __restrict__ ec,
    unsigned int* __restrict__ bitmap, int* __restrict__ cnt,
    int* __restrict__ cols, int E)
{
    int e = blockIdx.x * 256 + threadIdx.x;
    if (e >= E) return;
    int r = er[e], c = ec[e];
    unsigned int idx = ((unsigned int)r << 12) | (unsigned int)c;
    unsigned int bit = 1u << (idx & 31);
    unsigned int old = atomicOr(&bitmap[idx >> 5], bit);
    if (!(old & bit)) {
        int slot = atomicAdd(&cnt[r], 1);
        if (slot < MAXDEG) cols[r * MAXDEG + slot] = c;
    }
}

// ---------------- fp32 -> bf16 elementwise (vectorized) ----------------
__global__ __launch_bounds__(256) void cvt_bf16(
    const float* __restrict__ in, unsigned short* __restrict__ out, int n4)
{
    int i = blockIdx.x * 256 + threadIdx.x;
    if (i >= n4) return;
    float4 v = *(const float4*)(in + (size_t)i * 4);
    us4 o; o.x = f2bf(v.x); o.y = f2bf(v.y); o.z = f2bf(v.z); o.w = f2bf(v.w);
    *(us4*)(out + (size_t)i * 4) = o;
}

// ---------------- W[h][k][j] fp32 -> Wt[h*256+j][K] bf16 (tiled transpose) ----------------
__global__ __launch_bounds__(256) void transpose_w(
    const float* __restrict__ W, unsigned short* __restrict__ Wt, int K)
{
    __shared__ float tile[32][33];
    int k0 = blockIdx.x * 32;
    int j0 = blockIdx.y * 32;
    int h  = blockIdx.z;
    int tj = threadIdx.x & 31;
    int tk = threadIdx.x >> 5;
#pragma unroll
    for (int it = 0; it < 4; ++it) {
        int kl = tk + it * 8;
        tile[kl][tj] = W[(size_t)h * K * 256 + (size_t)(k0 + kl) * 256 + j0 + tj];
    }
    __syncthreads();
#pragma unroll
    for (int it = 0; it < 4; ++it) {
        int jl = tk + it * 8;
        Wt[(size_t)(h * 256 + j0 + jl) * K + k0 + tj] = f2bf(tile[tj][jl]);
    }
}

// ---------------- bf16 MFMA GEMM, 64x64 tile, BK=64, double-buffered 2-phase ----
// Main blocks (bn<16): h_all slice -> bf16 + fused wh1/wh2 (layout [node][4]) + colsum.
// Proj blocks (bn>=16, HASPROJ only): fp32 + bias into Cproj (stride 256).
template <int HASPROJ>
__global__ __launch_bounds__(256) void gemm_mfma(
    const unsigned short* __restrict__ A, const unsigned short* __restrict__ Bt,
    const unsigned short* __restrict__ pBt, const float* __restrict__ pb,
    float* __restrict__ Cproj, unsigned short* __restrict__ Cbf,
    const float* __restrict__ av, float* __restrict__ wh1, float* __restrict__ wh2,
    float* __restrict__ colsum, int K)
{
    __shared__ unsigned short As[2 * 64 * 64];   // 2 bufs x 64 rows x 128B
    __shared__ unsigned short Bs[2 * 64 * 64];
    int tid = threadIdx.x;
    int lane = tid & 63;
    int wave = tid >> 6;
    int wr = wave >> 1, wc = wave & 1;
    int bn = blockIdx.x, bm = blockIdx.y;
    int tileM = bm * 64;
    bool isProj = HASPROJ && (bn >= 16);
    const unsigned short* B = isProj ? pBt + (size_t)(bn - 16) * 64 * K
                                     : Bt + (size_t)bn * 64 * K;

    f32x4 acc[2][2];
#pragma unroll
    for (int m = 0; m < 2; ++m)
#pragma unroll
        for (int n = 0; n < 2; ++n) acc[m][n] = (f32x4){0.f, 0.f, 0.f, 0.f};

    // staging: thread covers (row = tid>>3, slot = tid&7) and (row+32, same slot)
    int srow = tid >> 3;
    int sslot = tid & 7;
    int gslot = sslot ^ (srow & 7);          // (srow+32)&7 == srow&7
    const unsigned short* gA0 = A + (size_t)(tileM + srow) * K + gslot * 8;
    const unsigned short* gA1 = A + (size_t)(tileM + 32 + srow) * K + gslot * 8;
    const unsigned short* gB0 = B + (size_t)srow * K + gslot * 8;
    const unsigned short* gB1 = B + (size_t)(32 + srow) * K + gslot * 8;

    int fr = lane & 15;
    int kq = lane >> 4;
    int nsteps = K >> 6;

    // prologue: stage tile 0 into buf 0
    gload_lds16(gA0, As + tid * 8);
    gload_lds16(gA1, As + 2048 + tid * 8);
    gload_lds16(gB0, Bs + tid * 8);
    gload_lds16(gB1, Bs + 2048 + tid * 8);
    gA0 += 64; gA1 += 64; gB0 += 64; gB1 += 64;
    __syncthreads();

    int cur = 0;
    for (int t = 0; t < nsteps; ++t) {
        if (t + 1 < nsteps) {                 // stage next tile while computing current
            int nb = (cur ^ 1) * 4096;
            gload_lds16(gA0, As + nb + tid * 8);
            gload_lds16(gA1, As + nb + 2048 + tid * 8);
            gload_lds16(gB0, Bs + nb + tid * 8);
            gload_lds16(gB1, Bs + nb + 2048 + tid * 8);
            gA0 += 64; gA1 += 64; gB0 += 64; gB1 += 64;
        }
        const unsigned short* Ab = As + cur * 4096;
        const unsigned short* Bb = Bs + cur * 4096;
        bf16x8 af[2][2], bfr[2][2];
#pragma unroll
        for (int m = 0; m < 2; ++m) {
            int row = wr * 32 + m * 16 + fr;
#pragma unroll
            for (int ks = 0; ks < 2; ++ks) {
                int sl = (ks * 4 + kq) ^ (row & 7);
                af[m][ks] = *(const bf16x8*)(Ab + row * 64 + sl * 8);
            }
        }
#pragma unroll
        for (int n = 0; n < 2; ++n) {
            int col = wc * 32 + n * 16 + fr;
#pragma unroll
            for (int ks = 0; ks < 2; ++ks) {
                int sl = (ks * 4 + kq) ^ (col & 7);
                bfr[n][ks] = *(const bf16x8*)(Bb + col * 64 + sl * 8);
            }
        }
#pragma unroll
        for (int m = 0; m < 2; ++m)
#pragma unroll
            for (int n = 0; n < 2; ++n)
#pragma unroll
                for (int ks = 0; ks < 2; ++ks)
                    acc[m][n] = __builtin_amdgcn_mfma_f32_16x16x32_bf16(
                        af[m][ks], bfr[n][ks], acc[m][n], 0, 0, 0);
        if (t + 1 < nsteps) __syncthreads();  // drains staged loads; protects buf reuse
        cur ^= 1;
    }

    int crow0 = tileM + wr * 32;

    if (!isProj) {
        int ccol0 = bn * 64 + wc * 32;
        int head = bn >> 2;
        // colsum atomics
#pragma unroll
        for (int n = 0; n < 2; ++n) {
            float s = 0.f;
#pragma unroll
            for (int m = 0; m < 2; ++m)
#pragma unroll
                for (int q = 0; q < 4; ++q) s += acc[m][n][q];
            s += __shfl_xor(s, 16);
            s += __shfl_xor(s, 32);
            if (kq == 0)
                atomicAdd(colsum + ccol0 + n * 16 + fr, s);
        }
        // wh1/wh2 fused row-dots, interleaved layout [node][4]
        float c1[2], c2[2];
#pragma unroll
        for (int n = 0; n < 2; ++n) {
            int j = (ccol0 + n * 16 + fr) & 255;
            c1[n] = av[head * 512 + j];
            c2[n] = av[head * 512 + 256 + j];
        }
#pragma unroll
        for (int m = 0; m < 2; ++m)
#pragma unroll
            for (int q = 0; q < 4; ++q) {
                float p1 = 0.f, p2 = 0.f;
#pragma unroll
                for (int n = 0; n < 2; ++n) {
                    p1 += acc[m][n][q] * c1[n];
                    p2 += acc[m][n][q] * c2[n];
                }
#pragma unroll
                for (int o = 1; o < 16; o <<= 1) {
                    p1 += __shfl_xor(p1, o);
                    p2 += __shfl_xor(p2, o);
                }
                if (fr == 0) {
                    int r = crow0 + m * 16 + kq * 4 + q;
                    atomicAdd(wh1 + r * 4 + head, p1);
                    atomicAdd(wh2 + r * 4 + head, p2);
                }
            }
        // bf16 C store (stride 1024)
#pragma unroll
        for (int m = 0; m < 2; ++m)
#pragma unroll
            for (int n = 0; n < 2; ++n) {
                int r0 = crow0 + m * 16 + kq * 4;
                int c  = ccol0 + n * 16 + fr;
#pragma unroll
                for (int q = 0; q < 4; ++q)
                    Cbf[(size_t)(r0 + q) * 1024 + c] = f2bf(acc[m][n][q]);
            }
    } else {
        int pcol0 = (bn - 16) * 64 + wc * 32;
#pragma unroll
        for (int m = 0; m < 2; ++m)
#pragma unroll
            for (int n = 0; n < 2; ++n) {
                int r0 = crow0 + m * 16 + kq * 4;
                int c  = pcol0 + n * 16 + fr;
                float bv = pb[c & 255];
#pragma unroll
                for (int q = 0; q < 4; ++q)
                    Cproj[(size_t)(r0 + q) * 256 + c] = acc[m][n][q] + bv;
            }
    }
}

// ---------------- per-row attention: 2 rows/block, uint4 gather, float4 wh ----------------
// 128 threads per row: head h = (t>>5)&3, feature-octet f = t&31 (8 features each).
__global__ __launch_bounds__(256) void row_attn(
    const unsigned short* __restrict__ h_bf, const float* __restrict__ wh1,
    const float* __restrict__ wh2, const float* __restrict__ colsum,
    const int* __restrict__ cnt, const int* __restrict__ cols,
    const float* __restrict__ bias, const float* __restrict__ prev,
    float* __restrict__ outp, unsigned short* __restrict__ out_bf, int N)
{
    int t = threadIdx.x;
    int rr = t >> 7;               // which of the 2 rows
    int tt = t & 127;
    int h = tt >> 5;               // head
    int f = tt & 31;               // feature-octet
    int i = blockIdx.x * 2 + rr;
    __shared__ int colsS[2][MAXDEG];
    __shared__ float wSt[2][MAXDEG][4];
    __shared__ float fsum[2][1024];
    int deg = cnt[i];
    if (deg > MAXDEG) deg = MAXDEG;
    if (tt < deg) colsS[rr][tt] = cols[i * MAXDEG + tt];
    __syncthreads();

    // edge weights: one float4 wh2 gather gives all 4 heads
    if (tt < deg) {
        int c = colsS[rr][tt];
        float4 w1 = *(const float4*)(wh1 + i * 4);
        float4 w2 = *(const float4*)(wh2 + c * 4);
        float s0 = w1.x + w2.x, s1 = w1.y + w2.y, s2 = w1.z + w2.z, s3 = w1.w + w2.w;
        s0 = s0 > 0.f ? s0 : 0.2f * s0;
        s1 = s1 > 0.f ? s1 : 0.2f * s1;
        s2 = s2 > 0.f ? s2 : 0.2f * s2;
        s3 = s3 > 0.f ? s3 : 0.2f * s3;
        wSt[rr][tt][0] = expf(s0) - 1.f;
        wSt[rr][tt][1] = expf(s1) - 1.f;
        wSt[rr][tt][2] = expf(s2) - 1.f;
        wSt[rr][tt][3] = expf(s3) - 1.f;
    }
    __syncthreads();

    float a[8] = {};
    float wsum = 0.f;
    const unsigned short* hb = h_bf + h * 256 + f * 8;
#pragma unroll 2
    for (int k = 0; k < deg; ++k) {
        float w = wSt[rr][k][h];
        uint4 v = *(const uint4*)(hb + (size_t)colsS[rr][k] * 1024);
        wsum += w;
        a[0] += w * __uint_as_float(v.x << 16);
        a[1] += w * __uint_as_float(v.x & 0xffff0000u);
        a[2] += w * __uint_as_float(v.y << 16);
        a[3] += w * __uint_as_float(v.y & 0xffff0000u);
        a[4] += w * __uint_as_float(v.z << 16);
        a[5] += w * __uint_as_float(v.z & 0xffff0000u);
        a[6] += w * __uint_as_float(v.w << 16);
        a[7] += w * __uint_as_float(v.w & 0xffff0000u);
    }
    float inv = 1.f / ((float)NNODES + wsum);
    float sq = 0.f;
    const float* cs = colsum + h * 256 + f * 8;
#pragma unroll
    for (int j = 0; j < 8; ++j) {
        float v = (cs[j] + a[j]) * inv;
        v = v > 0.f ? v : 0.2f * v;
        a[j] = v;
        sq += v * v;
    }
#pragma unroll
    for (int o = 1; o < 32; o <<= 1) sq += __shfl_xor(sq, o);   // 32-lane group = one head
    float rinv = 1.f / fmaxf(sqrtf(sq), 1e-12f);
    const float* bb = bias + h * 256 + f * 8;
    f32x4 lo, hi;
#pragma unroll
    for (int j = 0; j < 4; ++j) lo[j] = a[j] * rinv + bb[j];
#pragma unroll
    for (int j = 0; j < 4; ++j) hi[j] = a[4 + j] * rinv + bb[4 + j];
    *(f32x4*)(&fsum[rr][h * 256 + f * 8])     = lo;
    *(f32x4*)(&fsum[rr][h * 256 + f * 8 + 4]) = hi;
    __syncthreads();

#pragma unroll
    for (int r2 = 0; r2 < 2; ++r2) {
        int ii = blockIdx.x * 2 + r2;
        float o = (fsum[r2][t] + fsum[r2][256 + t] + fsum[r2][512 + t] + fsum[r2][768 + t]) * 0.25f
                  + prev[(size_t)ii * 256 + t];
        o = o > 0.f ? o : (expf(o) - 1.f);
        outp[(size_t)ii * 256 + t] = o;
        out_bf[(size_t)ii * 256 + t] = f2bf(o);
    }
}

extern "C" void kernel_launch(void* const* d_in, const int* in_sizes, int n_in,
                              void* d_out, int out_size, void* d_ws, size_t ws_size,
                              hipStream_t stream)
{
    const float* x  = (const float*)d_in[0];
    const int*   ei = (const int*)d_in[1];
    const float* W1 = (const float*)d_in[2];
    const float* a1 = (const float*)d_in[3];
    const float* b1 = (const float*)d_in[4];
    const float* Wk = (const float*)d_in[5];
    const float* ak = (const float*)d_in[6];
    const float* bk = (const float*)d_in[7];
    const float* pW = (const float*)d_in[8];
    const float* pb = (const float*)d_in[9];
    const int N = NNODES;
    const int E = in_sizes[1] / 2;
    const int* er = ei;
    const int* ec = ei + E;

    float* ws = (float*)d_ws;
    size_t off = 0;
    float* bufA    = ws + off; off += (size_t)N * 256;
    float* bufProj = ws + off; off += (size_t)N * 256;
    float* wh1     = ws + off; off += (size_t)NHEADS * N;
    float* wh2     = ws + off; off += (size_t)NHEADS * N;
    float* colsum  = ws + off; off += 1024;
    int*   cnt     = (int*)(ws + off); off += N;
    int*   cols    = (int*)(ws + off); off += (size_t)N * MAXDEG;
    unsigned int* bitmap = (unsigned int*)(ws + off); off += (size_t)N * N / 32;
    unsigned short* h_bf  = (unsigned short*)(ws + off); off += (size_t)N * 1024 / 2;
    unsigned short* xb    = (unsigned short*)(ws + off); off += (size_t)N * 512 / 2;
    unsigned short* bufAb = (unsigned short*)(ws + off); off += (size_t)N * 256 / 2;
    unsigned short* Wt1   = (unsigned short*)(ws + off); off += (size_t)4 * 256 * 512 / 2;
    unsigned short* Wtk   = (unsigned short*)(ws + off); off += (size_t)12 * 256 * 256 / 2;
    unsigned short* pWt   = (unsigned short*)(ws + off); off += (size_t)256 * 512 / 2;

    hipMemsetAsync(cnt, 0, N * sizeof(int), stream);
    hipMemsetAsync(bitmap, 0, (size_t)N * N / 8, stream);
    build_csr<<<(E + 255) / 256, 256, 0, stream>>>(er, ec, bitmap, cnt, cols, E);

    cvt_bf16<<<(N * 512 / 4 + 255) / 256, 256, 0, stream>>>(x, xb, N * 512 / 4);
    transpose_w<<<dim3(16, 8, 1), 256, 0, stream>>>(pW, pWt, 512);
    transpose_w<<<dim3(16, 8, 4), 256, 0, stream>>>(W1, Wt1, 512);
    transpose_w<<<dim3(8, 8, 12), 256, 0, stream>>>(Wk, Wtk, 256);

    for (int l = 0; l < 4; ++l) {
        int K = (l == 0) ? 512 : 256;
        const unsigned short* Wt = (l == 0) ? Wt1 : Wtk + (size_t)(l - 1) * 4 * 256 * 256;
        const float* av = (l == 0) ? a1 : ak + (size_t)(l - 1) * NHEADS * 512;
        const float* bv = (l == 0) ? b1 : bk + (size_t)(l - 1) * NHEADS * 256;
        const unsigned short* Ab = (l == 0) ? xb : bufAb;

        // zero wh1 | wh2 | colsum (contiguous) for the fused-epilogue atomics
        hipMemsetAsync(wh1, 0, (2 * NHEADS * N + 1024) * sizeof(float), stream);
        if (l == 0)
            gemm_mfma<1><<<dim3(20, 64), 256, 0, stream>>>(
                Ab, Wt, pWt, pb, bufProj, h_bf, av, wh1, wh2, colsum, K);
        else
            gemm_mfma<0><<<dim3(16, 64), 256, 0, stream>>>(
                Ab, Wt, nullptr, nullptr, nullptr, h_bf, av, wh1, wh2, colsum, K);

        const float* prev = (l == 0) ? bufProj : bufA;
        float* outp = (l == 3) ? (float*)d_out : bufA;
        row_attn<<<N / 2, 256, 0, stream>>>(h_bf, wh1, wh2, colsum, cnt, cols, bv, prev, outp, bufAb, N);
    }
}

// Round 6
// 239.345 us; speedup vs baseline: 1.1916x; 1.1916x over previous
//
#include <hip/hip_runtime.h>
#include <hip/hip_bf16.h>
#include <math.h>

#define NNODES 4096
#define NHEADS 4
#define MAXDEG 128

typedef __attribute__((ext_vector_type(8))) short  bf16x8;
typedef __attribute__((ext_vector_type(4))) float  f32x4;
typedef __attribute__((ext_vector_type(4))) unsigned short us4;

__device__ __forceinline__ unsigned short f2bf(float v) {
    unsigned int x = __float_as_uint(v);
    unsigned int r = (x + 0x7fffu + ((x >> 16) & 1u)) >> 16;   // RNE
    return (unsigned short)r;
}

__device__ __forceinline__ void gload_lds16(const unsigned short* g, unsigned short* l) {
    __builtin_amdgcn_global_load_lds(
        (const __attribute__((address_space(1))) unsigned int*)(g),
        (__attribute__((address_space(3))) unsigned int*)(l), 16, 0, 0);
}

// ---------------- CSR build with bitmap dedupe ----------------
__global__ __launch_bounds__(256) void build_csr(
    const int* __restrict__ er, const int* __restrict__ ec,
    unsigned int* __restrict__ bitmap, int* __restrict__ cnt,
    int* __restrict__ cols, int E)
{
    int e = blockIdx.x * 256 + threadIdx.x;
    if (e >= E) return;
    int r = er[e], c = ec[e];
    unsigned int idx = ((unsigned int)r << 12) | (unsigned int)c;
    unsigned int bit = 1u << (idx & 31);
    unsigned int old = atomicOr(&bitmap[idx >> 5], bit);
    if (!(old & bit)) {
        int slot = atomicAdd(&cnt[r], 1);
        if (slot < MAXDEG) cols[r * MAXDEG + slot] = c;
    }
}

// ---------------- fp32 -> bf16 elementwise (vectorized) ----------------
__global__ __launch_bounds__(256) void cvt_bf16(
    const float* __restrict__ in, unsigned short* __restrict__ out, int n4)
{
    int i = blockIdx.x * 256 + threadIdx.x;
    if (i >= n4) return;
    float4 v = *(const float4*)(in + (size_t)i * 4);
    us4 o; o.x = f2bf(v.x); o.y = f2bf(v.y); o.z = f2bf(v.z); o.w = f2bf(v.w);
    *(us4*)(out + (size_t)i * 4) = o;
}

// ---------------- W[h][k][j] fp32 -> Wt[h*256+j][K] bf16 (tiled transpose) ----------------
__global__ __launch_bounds__(256) void transpose_w(
    const float* __restrict__ W, unsigned short* __restrict__ Wt, int K)
{
    __shared__ float tile[32][33];
    int k0 = blockIdx.x * 32;
    int j0 = blockIdx.y * 32;
    int h  = blockIdx.z;
    int tj = threadIdx.x & 31;
    int tk = threadIdx.x >> 5;
#pragma unroll
    for (int it = 0; it < 4; ++it) {
        int kl = tk + it * 8;
        tile[kl][tj] = W[(size_t)h * K * 256 + (size_t)(k0 + kl) * 256 + j0 + tj];
    }
    __syncthreads();
#pragma unroll
    for (int it = 0; it < 4; ++it) {
        int jl = tk + it * 8;
        Wt[(size_t)(h * 256 + j0 + jl) * K + k0 + tj] = f2bf(tile[tj][jl]);
    }
}

// ---------------- bf16 MFMA GEMM, 64x64 tile, BK=32, depth-2 pipeline ----------
// 3 LDS buffers (24 KB), stage issued 2 K-steps ahead, counted vmcnt(2) + raw
// barrier (loads stay in flight across barriers — never drain to 0 mid-loop).
// Main blocks (bn<16): h slice -> bf16 + fused wh1/wh2 + colsum atomics.
// Proj blocks (bn>=16, HASPROJ only): fp32 + bias into Cproj (stride 256).
template <int HASPROJ>
__global__ __launch_bounds__(256) void gemm_mfma(
    const unsigned short* __restrict__ A, const unsigned short* __restrict__ Bt,
    const unsigned short* __restrict__ pBt, const float* __restrict__ pb,
    float* __restrict__ Cproj, unsigned short* __restrict__ Cbf,
    const float* __restrict__ av, float* __restrict__ wh1, float* __restrict__ wh2,
    float* __restrict__ colsum, int K)
{
    __shared__ unsigned short As[3 * 64 * 32];   // 3 bufs x 64 rows x 64B
    __shared__ unsigned short Bs[3 * 64 * 32];
    int tid = threadIdx.x;
    int lane = tid & 63;
    int wave = tid >> 6;
    int wr = wave >> 1, wc = wave & 1;
    int bn = blockIdx.x, bm = blockIdx.y;
    int tileM = bm * 64;
    bool isProj = HASPROJ && (bn >= 16);
    const unsigned short* B = isProj ? pBt + (size_t)(bn - 16) * 64 * K
                                     : Bt + (size_t)bn * 64 * K;

    f32x4 acc[2][2];
#pragma unroll
    for (int m = 0; m < 2; ++m)
#pragma unroll
        for (int n = 0; n < 2; ++n) acc[m][n] = (f32x4){0.f, 0.f, 0.f, 0.f};

    // staging: thread t -> (srow = t>>2, sslot = t&3); swizzled global column chunk
    int srow = tid >> 2;
    int sslot = tid & 3;
    int gslot = sslot ^ ((srow >> 1) & 3);
    const unsigned short* gA = A + (size_t)(tileM + srow) * K + gslot * 8;
    const unsigned short* gB = B + (size_t)srow * K + gslot * 8;
    unsigned short* lA = As + tid * 8;
    unsigned short* lB = Bs + tid * 8;

    int fr = lane & 15;
    int kq = lane >> 4;
    int nsteps = K >> 5;          // 8 (K=256) or 16 (K=512)

    // prologue: stage steps 0 and 1
    gload_lds16(gA, lA);             gload_lds16(gB, lB);
    gload_lds16(gA + 32, lA + 2048); gload_lds16(gB + 32, lB + 2048);

    // read offsets (ushort units) within a buffer, for this lane's fragments
    int aoff[2], boff[2];
#pragma unroll
    for (int m = 0; m < 2; ++m) {
        int row = wr * 32 + m * 16 + fr;
        aoff[m] = row * 32 + ((kq ^ ((row >> 1) & 3)) << 3);
    }
#pragma unroll
    for (int n = 0; n < 2; ++n) {
        int col = wc * 32 + n * 16 + fr;
        boff[n] = col * 32 + ((kq ^ ((col >> 1) & 3)) << 3);
    }

    for (int t = 0; t < nsteps; ++t) {
        // wait for stage(t) (2 newest loads = stage(t+1) may still fly)
        if (t + 1 < nsteps) {
            asm volatile("s_waitcnt vmcnt(2)" ::: "memory");
        } else {
            asm volatile("s_waitcnt vmcnt(0)" ::: "memory");
        }
        __builtin_amdgcn_sched_barrier(0);
        __builtin_amdgcn_s_barrier();   // all waves: stage(t) landed, buf[(t+2)%3] free
        if (t + 2 < nsteps) {
            int b2 = (t + 2) % 3;
            gload_lds16(gA + (size_t)(t + 2) * 32, lA + b2 * 2048);
            gload_lds16(gB + (size_t)(t + 2) * 32, lB + b2 * 2048);
        }
        const unsigned short* Ab = As + (t % 3) * 2048;
        const unsigned short* Bb = Bs + (t % 3) * 2048;
        bf16x8 af[2], bf[2];
#pragma unroll
        for (int m = 0; m < 2; ++m) af[m] = *(const bf16x8*)(Ab + aoff[m]);
#pragma unroll
        for (int n = 0; n < 2; ++n) bf[n] = *(const bf16x8*)(Bb + boff[n]);
#pragma unroll
        for (int m = 0; m < 2; ++m)
#pragma unroll
            for (int n = 0; n < 2; ++n)
                acc[m][n] = __builtin_amdgcn_mfma_f32_16x16x32_bf16(
                    af[m], bf[n], acc[m][n], 0, 0, 0);
    }

    int crow0 = tileM + wr * 32;

    if (!isProj) {
        int ccol0 = bn * 64 + wc * 32;
        int head = bn >> 2;
        // colsum atomics
#pragma unroll
        for (int n = 0; n < 2; ++n) {
            float s = 0.f;
#pragma unroll
            for (int m = 0; m < 2; ++m)
#pragma unroll
                for (int q = 0; q < 4; ++q) s += acc[m][n][q];
            s += __shfl_xor(s, 16);
            s += __shfl_xor(s, 32);
            if (kq == 0)
                atomicAdd(colsum + ccol0 + n * 16 + fr, s);
        }
        // wh1/wh2 fused row-dots (head-major layout, as benched at 232us)
        float c1[2], c2[2];
#pragma unroll
        for (int n = 0; n < 2; ++n) {
            int j = (ccol0 + n * 16 + fr) & 255;
            c1[n] = av[head * 512 + j];
            c2[n] = av[head * 512 + 256 + j];
        }
#pragma unroll
        for (int m = 0; m < 2; ++m)
#pragma unroll
            for (int q = 0; q < 4; ++q) {
                float p1 = 0.f, p2 = 0.f;
#pragma unroll
                for (int n = 0; n < 2; ++n) {
                    p1 += acc[m][n][q] * c1[n];
                    p2 += acc[m][n][q] * c2[n];
                }
#pragma unroll
                for (int o = 1; o < 16; o <<= 1) {
                    p1 += __shfl_xor(p1, o);
                    p2 += __shfl_xor(p2, o);
                }
                if (fr == 0) {
                    int r = crow0 + m * 16 + kq * 4 + q;
                    atomicAdd(wh1 + head * NNODES + r, p1);
                    atomicAdd(wh2 + head * NNODES + r, p2);
                }
            }
        // bf16 C store (stride 1024)
#pragma unroll
        for (int m = 0; m < 2; ++m)
#pragma unroll
            for (int n = 0; n < 2; ++n) {
                int r0 = crow0 + m * 16 + kq * 4;
                int c  = ccol0 + n * 16 + fr;
#pragma unroll
                for (int q = 0; q < 4; ++q)
                    Cbf[(size_t)(r0 + q) * 1024 + c] = f2bf(acc[m][n][q]);
            }
    } else {
        int pcol0 = (bn - 16) * 64 + wc * 32;
#pragma unroll
        for (int m = 0; m < 2; ++m)
#pragma unroll
            for (int n = 0; n < 2; ++n) {
                int r0 = crow0 + m * 16 + kq * 4;
                int c  = pcol0 + n * 16 + fr;
                float bv = pb[c & 255];
#pragma unroll
                for (int q = 0; q < 4; ++q)
                    Cproj[(size_t)(r0 + q) * 256 + c] = acc[m][n][q] + bv;
            }
    }
}

// ---------------- per-row attention: all 4 heads in one gather pass ----------------
// wave h = head h; lane f covers features 4f..4f+3 (uint2 = 4 bf16 per neighbor).
__global__ __launch_bounds__(256) void row_attn(
    const unsigned short* __restrict__ h_bf, const float* __restrict__ wh1,
    const float* __restrict__ wh2, const float* __restrict__ colsum,
    const int* __restrict__ cnt, const int* __restrict__ cols,
    const float* __restrict__ bias, const float* __restrict__ prev,
    float* __restrict__ outp, unsigned short* __restrict__ out_bf, int N)
{
    int i = blockIdx.x;
    int t = threadIdx.x;
    int h = t >> 6, f = t & 63;
    __shared__ int colsS[MAXDEG];
    __shared__ float wS[4][MAXDEG];
    __shared__ float fsum[1024];
    int deg = cnt[i];
    if (deg > MAXDEG) deg = MAXDEG;
    if (t < deg) colsS[t] = cols[i * MAXDEG + t];
    __syncthreads();

    {   // edge weights for all 4 heads: 2 head-pairs x 128 threads
        int k = t & 127;
        int hh0 = t >> 7;
#pragma unroll
        for (int p = 0; p < 2; ++p) {
            int hh = 2 * p + hh0;
            if (k < deg) {
                float s = wh1[hh * N + i] + wh2[hh * N + colsS[k]];
                s = s > 0.f ? s : 0.2f * s;
                wS[hh][k] = expf(s) - 1.f;
            }
        }
    }
    __syncthreads();

    float a0 = 0.f, a1 = 0.f, a2 = 0.f, a3 = 0.f, wsum = 0.f;
    const unsigned short* hb = h_bf + h * 256 + f * 4;
    for (int k = 0; k < deg; ++k) {
        float w = wS[h][k];
        uint2 v = *(const uint2*)(hb + (size_t)colsS[k] * 1024);
        wsum += w;
        a0 += w * __uint_as_float(v.x << 16);
        a1 += w * __uint_as_float(v.x & 0xffff0000u);
        a2 += w * __uint_as_float(v.y << 16);
        a3 += w * __uint_as_float(v.y & 0xffff0000u);
    }
    float inv = 1.f / ((float)NNODES + wsum);
    float4 cs = *(const float4*)(colsum + h * 256 + f * 4);
    float v0 = (cs.x + a0) * inv, v1 = (cs.y + a1) * inv;
    float v2 = (cs.z + a2) * inv, v3 = (cs.w + a3) * inv;
    v0 = v0 > 0.f ? v0 : 0.2f * v0;
    v1 = v1 > 0.f ? v1 : 0.2f * v1;
    v2 = v2 > 0.f ? v2 : 0.2f * v2;
    v3 = v3 > 0.f ? v3 : 0.2f * v3;
    float sq = v0 * v0 + v1 * v1 + v2 * v2 + v3 * v3;
#pragma unroll
    for (int o = 1; o < 64; o <<= 1) sq += __shfl_xor(sq, o);
    float rinv = 1.f / fmaxf(sqrtf(sq), 1e-12f);
    float4 bb = *(const float4*)(bias + h * 256 + f * 4);
    f32x4 fv;
    fv[0] = v0 * rinv + bb.x; fv[1] = v1 * rinv + bb.y;
    fv[2] = v2 * rinv + bb.z; fv[3] = v3 * rinv + bb.w;
    *(f32x4*)(fsum + h * 256 + f * 4) = fv;
    __syncthreads();
    float o = (fsum[t] + fsum[256 + t] + fsum[512 + t] + fsum[768 + t]) * 0.25f
              + prev[(size_t)i * 256 + t];
    o = o > 0.f ? o : (expf(o) - 1.f);
    outp[(size_t)i * 256 + t] = o;
    out_bf[(size_t)i * 256 + t] = f2bf(o);
}

extern "C" void kernel_launch(void* const* d_in, const int* in_sizes, int n_in,
                              void* d_out, int out_size, void* d_ws, size_t ws_size,
                              hipStream_t stream)
{
    const float* x  = (const float*)d_in[0];
    const int*   ei = (const int*)d_in[1];
    const float* W1 = (const float*)d_in[2];
    const float* a1 = (const float*)d_in[3];
    const float* b1 = (const float*)d_in[4];
    const float* Wk = (const float*)d_in[5];
    const float* ak = (const float*)d_in[6];
    const float* bk = (const float*)d_in[7];
    const float* pW = (const float*)d_in[8];
    const float* pb = (const float*)d_in[9];
    const int N = NNODES;
    const int E = in_sizes[1] / 2;
    const int* er = ei;
    const int* ec = ei + E;

    float* ws = (float*)d_ws;
    size_t off = 0;
    float* bufA    = ws + off; off += (size_t)N * 256;
    float* bufProj = ws + off; off += (size_t)N * 256;
    float* wh1     = ws + off; off += (size_t)NHEADS * N;
    float* wh2     = ws + off; off += (size_t)NHEADS * N;
    float* colsum  = ws + off; off += 1024;
    int*   cnt     = (int*)(ws + off); off += N;
    int*   cols    = (int*)(ws + off); off += (size_t)N * MAXDEG;
    unsigned int* bitmap = (unsigned int*)(ws + off); off += (size_t)N * N / 32;
    unsigned short* h_bf  = (unsigned short*)(ws + off); off += (size_t)N * 1024 / 2;
    unsigned short* xb    = (unsigned short*)(ws + off); off += (size_t)N * 512 / 2;
    unsigned short* bufAb = (unsigned short*)(ws + off); off += (size_t)N * 256 / 2;
    unsigned short* Wt1   = (unsigned short*)(ws + off); off += (size_t)4 * 256 * 512 / 2;
    unsigned short* Wtk   = (unsigned short*)(ws + off); off += (size_t)12 * 256 * 256 / 2;
    unsigned short* pWt   = (unsigned short*)(ws + off); off += (size_t)256 * 512 / 2;

    hipMemsetAsync(cnt, 0, N * sizeof(int), stream);
    hipMemsetAsync(bitmap, 0, (size_t)N * N / 8, stream);
    build_csr<<<(E + 255) / 256, 256, 0, stream>>>(er, ec, bitmap, cnt, cols, E);

    cvt_bf16<<<(N * 512 / 4 + 255) / 256, 256, 0, stream>>>(x, xb, N * 512 / 4);
    transpose_w<<<dim3(16, 8, 1), 256, 0, stream>>>(pW, pWt, 512);
    transpose_w<<<dim3(16, 8, 4), 256, 0, stream>>>(W1, Wt1, 512);
    transpose_w<<<dim3(8, 8, 12), 256, 0, stream>>>(Wk, Wtk, 256);

    for (int l = 0; l < 4; ++l) {
        int K = (l == 0) ? 512 : 256;
        const unsigned short* Wt = (l == 0) ? Wt1 : Wtk + (size_t)(l - 1) * 4 * 256 * 256;
        const float* av = (l == 0) ? a1 : ak + (size_t)(l - 1) * NHEADS * 512;
        const float* bv = (l == 0) ? b1 : bk + (size_t)(l - 1) * NHEADS * 256;
        const unsigned short* Ab = (l == 0) ? xb : bufAb;

        // zero wh1 | wh2 | colsum (contiguous) for the fused-epilogue atomics
        hipMemsetAsync(wh1, 0, (2 * NHEADS * N + 1024) * sizeof(float), stream);
        if (l == 0)
            gemm_mfma<1><<<dim3(20, 64), 256, 0, stream>>>(
                Ab, Wt, pWt, pb, bufProj, h_bf, av, wh1, wh2, colsum, K);
        else
            gemm_mfma<0><<<dim3(16, 64), 256, 0, stream>>>(
                Ab, Wt, nullptr, nullptr, nullptr, h_bf, av, wh1, wh2, colsum, K);

        const float* prev = (l == 0) ? bufProj : bufA;
        float* outp = (l == 3) ? (float*)d_out : bufA;
        row_attn<<<N, 256, 0, stream>>>(h_bf, wh1, wh2, colsum, cnt, cols, bv, prev, outp, bufAb, N);
    }
}